// Round 5
// baseline (544.864 us; speedup 1.0000x reference)
//
#include <hip/hip_runtime.h>
#include <math.h>

#define BB 4
#define NN 2000
#define KK 5
#define DD 32
#define H1 160
#define HEAD 5
#define HDIM 32
#define MAXNORM 0.996f
#define MINN 1e-15f

// ---- streaming scan geometry ----
// in_nei is [B*N*K = 40000][N = 2000] floats = 80,000,000 floats = 20,000,000 float4.
#define NROWS (BB * NN * KK)        // 40000
#define NF4   (NROWS * (NN / 4))    // 20,000,000 float4 elements
#define F4_PER_ROW (NN / 4)         // 500
#define G_BLOCKS 2000               // 8000 g-rows, 4 waves/block
#define SCAN_BLOCKS 9766            // ceil(NF4 / (256*8)) -> 8 float4 per thread
#define SCAN_STRIDE (SCAN_BLOCKS * 256)  // 2,500,096 float4 between a thread's loads

typedef float vfloat4 __attribute__((ext_vector_type(4)));

__device__ __forceinline__ float artanh_f(float x) {
    x = fminf(fmaxf(x, -1.0f + 1e-7f), 1.0f - 1e-7f);
    return 0.5f * (log1pf(x) - log1pf(-x));
}

// sum over a full 64-lane wave
__device__ __forceinline__ float wave_sum(float v) {
#pragma unroll
    for (int o = 32; o > 0; o >>= 1) v += __shfl_xor(v, o, 64);
    return v;
}

// sum within each 32-lane half (both halves hold identical data in our usage)
__device__ __forceinline__ float wave_sum32(float v) {
#pragma unroll
    for (int o = 16; o > 0; o >>= 1) v += __shfl_xor(v, o, 64);
    return v;
}

// ---------------- scan kernel: pure stream, thread-per-float4, CACHED loads ----
// 8 fully independent coalesced float4 loads per thread, zero cross-lane ops,
// unconstrained VGPR budget (all 8 loads in flight). NORMAL loads, not NT:
// in_nei is read-only and partially survives in the 256 MB L3 across bench
// iterations (R2 counters: FETCH 209 MB < 308 MB read => ~100 MB L3 hits even
// before we let it allocate). NT loads (R4) forbade that reuse — removed.
__global__ __launch_bounds__(256) void scan_kernel(const float* __restrict__ nei,
                                                   int* __restrict__ idx) {
    unsigned t = blockIdx.x * 256u + threadIdx.x;   // 0 .. SCAN_STRIDE-1
    const vfloat4* __restrict__ p = (const vfloat4*)nei;
    vfloat4 v[8];
#pragma unroll
    for (int j = 0; j < 8; ++j) {
        unsigned e = t + (unsigned)j * SCAN_STRIDE;
        if (e < NF4) v[j] = p[e];
    }
#pragma unroll
    for (int j = 0; j < 8; ++j) {
        unsigned e = t + (unsigned)j * SCAN_STRIDE;
        if (e < NF4) {
            int sub = -1;
            if (v[j][0] > 0.5f) sub = 0;
            if (v[j][1] > 0.5f) sub = 1;
            if (v[j][2] > 0.5f) sub = 2;
            if (v[j][3] > 0.5f) sub = 3;
            if (sub >= 0) {
                unsigned row = e / F4_PER_ROW;              // magic-mul division
                unsigned col = (e - row * F4_PER_ROW) * 4u + (unsigned)sub;
                idx[row] = (int)col;                        // one-hot: unique writer
            }
        }
    }
}

// ---------------- g kernel: g[row,0:160] = logmap0(hnn1(proj(expmap0(logmap0(x))))) ----
// Analytic-norm chain: |expmap0(u)| = tanh(|u|), |logmap0(p)| = artanh(|p|),
// |proj(x)| = min(|x|, MAXNORM), |s*x| = s*|x|. Only 6 reductions are genuine.
__global__ __launch_bounds__(256, 4) void g_kernel(const float* __restrict__ xin,
                                                   const float* __restrict__ W1,
                                                   const float* __restrict__ b1,
                                                   float* __restrict__ g) {
    int lane = threadIdx.x & 63;
    int wave = (int)blockIdx.x * 4 + (int)(threadIdx.x >> 6);  // 0..7999
    bool j2ok = lane < (H1 - 128);  // lane < 32 handles third chunk

    // --- load agent row (lanes 0..31 hold components) ---
    float x = (lane < DD) ? xin[wave * DD + lane] : 0.f;

    // feats = logmap0(x)
    float n = fmaxf(sqrtf(wave_sum(x * x)), MINN);          // reduce #1
    float fa = artanh_f(n);
    float f = (fa / n) * x;
    // p = proj(expmap0(feats));  |f| = artanh(n), |p| = tanh(|f|)
    float fn = fmaxf(fa, MINN);
    float tp = tanhf(fn);
    float p = (tp / fn) * f;
    float pn = tp;
    if (pn > MAXNORM) p *= MAXNORM / pn;
    float xn = fmaxf(fminf(pn, MAXNORM), MINN);             // |p| after proj

    // mx = W1 @ p  (each lane: rows lane, lane+64, lane+128)
    float mx0 = 0.f, mx1 = 0.f, mx2 = 0.f;
#pragma unroll
    for (int d = 0; d < DD; ++d) {
        float pd = __shfl(p, d, 64);
        mx0 += W1[lane * DD + d] * pd;
        mx1 += W1[(lane + 64) * DD + d] * pd;
        if (j2ok) mx2 += W1[(lane + 128) * DD + d] * pd;
    }
    float m2 = mx0 * mx0 + mx1 * mx1 + (j2ok ? mx2 * mx2 : 0.f);
    float mxn = fmaxf(sqrtf(wave_sum(m2)), MINN);           // reduce #2
    float tr = tanhf(mxn / xn * artanh_f(xn));
    float sc = tr / mxn;
    float r0 = sc * mx0, r1 = sc * mx1, r2 = sc * mx2;
    // proj: |r| = tr (tanh arg positive)
    float rn = tr;
    if (rn > MAXNORM) { float s = MAXNORM / rn; r0 *= s; r1 *= s; r2 *= s; }
    rn = fminf(rn, MAXNORM);

    // hb = proj(expmap0(b1))  (b1 == 0 in practice; general path kept)
    float bb0 = b1[lane], bb1 = b1[lane + 64], bb2 = j2ok ? b1[lane + 128] : 0.f;
    float bn = fmaxf(sqrtf(wave_sum(bb0 * bb0 + bb1 * bb1 + bb2 * bb2)), MINN);  // reduce #3
    float tb = tanhf(bn);
    float bs = tb / bn;
    float h0 = bs * bb0, h1 = bs * bb1, h2 = bs * bb2;
    float hn = tb;
    if (hn > MAXNORM) { float s = MAXNORM / hn; h0 *= s; h1 *= s; h2 *= s; }
    hn = fminf(hn, MAXNORM);

    // mobius_add(r, h): x2s = rn^2, y2s = hn^2 analytic; only cross term reduced
    float x2s = rn * rn;
    float y2s = hn * hn;
    float xys = wave_sum(r0 * h0 + r1 * h1 + (j2ok ? r2 * h2 : 0.f));  // reduce #4
    float ca = 1.f + 2.f * xys + y2s;
    float cb = 1.f - x2s;
    float den = fmaxf(1.f + 2.f * xys + x2s * y2s, MINN);
    float a0 = (ca * r0 + cb * h0) / den;
    float a1 = (ca * r1 + cb * h1) / den;
    float a2 = (ca * r2 + cb * h2) / den;
    // proj
    float an = fmaxf(sqrtf(wave_sum(a0 * a0 + a1 * a1 + (j2ok ? a2 * a2 : 0.f))), MINN);  // reduce #5
    if (an > MAXNORM) { float s = MAXNORM / an; a0 *= s; a1 *= s; a2 *= s; }
    float an2 = fmaxf(fminf(an, MAXNORM), MINN);

    // xt = relu(logmap0(a)) — relu changes the norm, so reduce again
    float ls = artanh_f(an2) / an2;
    float t0 = fmaxf(ls * a0, 0.f), t1 = fmaxf(ls * a1, 0.f), t2 = fmaxf(ls * a2, 0.f);
    float tn = fmaxf(sqrtf(wave_sum(t0 * t0 + t1 * t1 + (j2ok ? t2 * t2 : 0.f))), MINN);  // reduce #6
    // y = proj(expmap0(xt)); |y| = tanh(tn); g = logmap0(y)
    float te = tanhf(tn);
    float es = te / tn;
    float y0 = es * t0, y1 = es * t1, y2 = es * t2;
    float yn = te;
    float s2 = (yn > MAXNORM) ? (MAXNORM / yn) : 1.f;
    y0 *= s2; y1 *= s2; y2 *= s2;
    float yn2 = fmaxf(fminf(yn, MAXNORM), MINN);
    float gs = artanh_f(yn2) / yn2;

    float* go = g + (size_t)wave * H1;
    go[lane] = gs * y0;
    go[lane + 64] = gs * y1;
    if (j2ok) go[lane + 128] = gs * y2;
}

// ---------------- Kernel 3: fused attention + output layer, wave per (b,n) --
__global__ __launch_bounds__(256, 4) void fused_att_out_kernel(const float* __restrict__ g,
                                                               const int* __restrict__ idx,
                                                               const float* __restrict__ W2,
                                                               const float* __restrict__ b2,
                                                               float* __restrict__ out,
                                                               float* __restrict__ att_out) {
    int wave = (blockIdx.x * blockDim.x + threadIdx.x) >> 6;
    int lane = threadIdx.x & 63;
    if (wave >= BB * NN) return;
    int r = wave;
    int b = r / NN;
    int d = lane & 31;  // both 32-halves do identical work

    // q[d][h]
    const float* gq = g + (size_t)r * H1;
    float q[HEAD];
#pragma unroll
    for (int h = 0; h < HEAD; ++h) q[h] = gq[d * HEAD + h];

    // load all 5 neighbor indices, then all 5 kv rows (max memory parallelism),
    // then reduce the 25 dot products
    int nb[KK];
#pragma unroll
    for (int k = 0; k < KK; ++k) nb[k] = idx[r * KK + k];
    float kv[KK][HEAD];
#pragma unroll
    for (int k = 0; k < KK; ++k) {
        const float* gk = g + (size_t)(b * NN + nb[k]) * H1 + d * HEAD;
#pragma unroll
        for (int h = 0; h < HEAD; ++h) kv[k][h] = gk[h];
    }
    float s[KK][HEAD];
#pragma unroll
    for (int k = 0; k < KK; ++k)
#pragma unroll
        for (int h = 0; h < HEAD; ++h) s[k][h] = wave_sum32(q[h] * kv[k][h]);

    // softmax over k per head (redundant per lane; all lanes hold s)
    float att[HEAD][KK];
#pragma unroll
    for (int h = 0; h < HEAD; ++h) {
        float mxv = s[0][h];
#pragma unroll
        for (int k = 1; k < KK; ++k) mxv = fmaxf(mxv, s[k][h]);
        float sum = 0.f;
#pragma unroll
        for (int k = 0; k < KK; ++k) { att[h][k] = expf(s[k][h] - mxv); sum += att[h][k]; }
        float inv = 1.f / sum;
#pragma unroll
        for (int k = 0; k < KK; ++k) att[h][k] *= inv;
    }
    // att_record: [r][h][k], lanes 0..24 write
    if (lane < HEAD * KK) {
        int h = lane / KK, k = lane % KK;
        att_out[(size_t)r * HEAD * KK + lane] = att[h][k];
    }

    // o[d] = mean over heads of sum_k att*kv
    float o = 0.f;
#pragma unroll
    for (int h = 0; h < HEAD; ++h)
#pragma unroll
        for (int k = 0; k < KK; ++k) o += att[h][k] * kv[k][h];
    o *= (1.f / HEAD);

    // ---- proj(expmap0(o)); |expmap0(o)| = tanh(|o|) ----
    float n = fmaxf(sqrtf(wave_sum32(o * o)), MINN);        // reduce #1
    float to = tanhf(n);
    o *= to / n;
    float on = to;
    if (on > MAXNORM) o *= MAXNORM / on;
    float xn = fmaxf(fminf(on, MAXNORM), MINN);

    // ---- hnn_layer(o, W2, b2) ----
    // mx[j] = W2[j,:] @ o  (j = lane&31)
    float mx = 0.f;
#pragma unroll
    for (int dd = 0; dd < HDIM; ++dd) {
        float od = __shfl(o, dd, 64);
        mx += W2[d * HDIM + dd] * od;
    }
    float mxn = fmaxf(sqrtf(wave_sum32(mx * mx)), MINN);    // reduce #2
    float tr = tanhf(mxn / xn * artanh_f(xn));
    mx *= tr / mxn;
    float rn = tr;
    if (rn > MAXNORM) mx *= MAXNORM / rn;
    rn = fminf(rn, MAXNORM);

    // hb = proj(expmap0(b2))
    float hb = b2[d];
    float bn = fmaxf(sqrtf(wave_sum32(hb * hb)), MINN);     // reduce #3
    float tb = tanhf(bn);
    hb *= tb / bn;
    float hn = tb;
    if (hn > MAXNORM) hb *= MAXNORM / hn;
    hn = fminf(hn, MAXNORM);

    // mobius_add(mx, hb): x2s/y2s analytic, cross term reduced
    float x2s = rn * rn;
    float y2s = hn * hn;
    float xys = wave_sum32(mx * hb);                        // reduce #4
    float ca = 1.f + 2.f * xys + y2s;
    float cb = 1.f - x2s;
    float den = fmaxf(1.f + 2.f * xys + x2s * y2s, MINN);
    float a = (ca * mx + cb * hb) / den;
    // proj
    float an = fmaxf(sqrtf(wave_sum32(a * a)), MINN);       // reduce #5
    if (an > MAXNORM) a *= MAXNORM / an;
    float an2 = fmaxf(fminf(an, MAXNORM), MINN);

    // xt = relu(logmap0(a))
    a = fmaxf((artanh_f(an2) / an2) * a, 0.f);
    // proj(expmap0(xt)); |expmap0(xt)| = tanh(|xt|)
    float tn = fmaxf(sqrtf(wave_sum32(a * a)), MINN);       // reduce #6
    float te = tanhf(tn);
    a *= te / tn;
    float yn = te;
    if (yn > MAXNORM) a *= MAXNORM / yn;

    if (lane < HDIM) out[(size_t)r * HDIM + lane] = a;
}

extern "C" void kernel_launch(void* const* d_in, const int* in_sizes, int n_in,
                              void* d_out, int out_size, void* d_ws, size_t ws_size,
                              hipStream_t stream) {
    const float* in_feats = (const float*)d_in[0];
    const float* in_nei = (const float*)d_in[1];
    const float* W1 = (const float*)d_in[2];
    const float* b1 = (const float*)d_in[3];
    const float* W2 = (const float*)d_in[4];
    const float* b2 = (const float*)d_in[5];

    // workspace layout: idx[40000] ints, then g[8000*160] floats
    int* idx = (int*)d_ws;
    size_t idx_bytes = ((size_t)BB * NN * KK * sizeof(int) + 255) & ~(size_t)255;
    float* g = (float*)((char*)d_ws + idx_bytes);

    float* out = (float*)d_out;                      // [B,N,32] = 256000 floats
    float* att = out + (size_t)BB * NN * HDIM;       // [B,N,head,K] = 200000 floats

    // Three kernels:
    // 1) g table (short, VALU-bound), 2) cached stream scan (HBM/L3-bound),
    // 3) fused attention + output layer (reads cache-warm g).
    hipLaunchKernelGGL(g_kernel, dim3(G_BLOCKS), dim3(256), 0, stream,
                       in_feats, W1, b1, g);
    hipLaunchKernelGGL(scan_kernel, dim3(SCAN_BLOCKS), dim3(256), 0, stream,
                       in_nei, idx);
    hipLaunchKernelGGL(fused_att_out_kernel, dim3((BB * NN * 64 + 255) / 256), dim3(256), 0, stream,
                       g, idx, W2, b2, out, att);
}

// Round 6
// 504.820 us; speedup vs baseline: 1.0793x; 1.0793x over previous
//
#include <hip/hip_runtime.h>
#include <math.h>

#define BB 4
#define NN 2000
#define KK 5
#define DD 32
#define H1 160
#define HEAD 5
#define HDIM 32
#define MAXNORM 0.996f
#define MINN 1e-15f

#define NROWS (BB * NN * KK)        // 40000 one-hot rows
#define F4_PER_ROW (NN / 4)         // 500 float4 per row
#define G_BLOCKS 2000               // 8000 g-rows, 4 waves/block
#define SCAN_BLOCKS (NROWS / 4)     // wave per row, 4 waves/block = 10000 blocks

typedef float vfloat4 __attribute__((ext_vector_type(4)));

__device__ __forceinline__ float artanh_f(float x) {
    x = fminf(fmaxf(x, -1.0f + 1e-7f), 1.0f - 1e-7f);
    return 0.5f * (log1pf(x) - log1pf(-x));
}

// sum over a full 64-lane wave
__device__ __forceinline__ float wave_sum(float v) {
#pragma unroll
    for (int o = 32; o > 0; o >>= 1) v += __shfl_xor(v, o, 64);
    return v;
}

// sum within each 32-lane half (both halves hold identical data in our usage)
__device__ __forceinline__ float wave_sum32(float v) {
#pragma unroll
    for (int o = 16; o > 0; o >>= 1) v += __shfl_xor(v, o, 64);
    return v;
}

// ---------------- scan: wave per row, TWO batches of 4 independent loads ----
// Overlap model (R0-R5): the harness's 1.28 GB poison-fill (6.6 TB/s writes)
// runs concurrently, capping our reads at ~1.4-1.8 TB/s. So minimize BYTES
// while keeping batched MLP: batch 1 = cols 0..1023 (4 KB, 4 independent
// float4/lane) resolves 51.2% of rows; batch 2 reads the remaining 3.9 KB.
// Expected ~240 MB total (vs 320 full-stream), only 2 dependent phases/wave.
// NT loads: zero reuse, and allocating into L3 forces dirty-fill writebacks
// (R5 cached regressed 25 us vs R4 NT).
__global__ __launch_bounds__(256) void scan_kernel(const float* __restrict__ nei,
                                                   int* __restrict__ idx) {
    int lane = threadIdx.x & 63;
    int wave = (int)((blockIdx.x * 256u + threadIdx.x) >> 6);   // 0..39999
    const vfloat4* __restrict__ row = (const vfloat4*)(nei + (size_t)wave * NN);
    int pos = -1;
    vfloat4 v[4];

    // batch 1: float4 indices lane + 64*j, j=0..3  -> cols 0..1023
#pragma unroll
    for (int j = 0; j < 4; ++j)
        v[j] = __builtin_nontemporal_load(row + (lane + 64 * j));
#pragma unroll
    for (int j = 0; j < 4; ++j) {
        int base = (lane + 64 * j) * 4;
        if (v[j][0] > 0.5f) pos = base;
        if (v[j][1] > 0.5f) pos = base + 1;
        if (v[j][2] > 0.5f) pos = base + 2;
        if (v[j][3] > 0.5f) pos = base + 3;
    }
    if (__ballot(pos >= 0) == 0ull) {
        // batch 2: float4 indices 256 + lane + 64*j, masked to < 500
#pragma unroll
        for (int j = 0; j < 4; ++j) {
            int e = 256 + lane + 64 * j;
            if (e < F4_PER_ROW) {
                v[j] = __builtin_nontemporal_load(row + e);
            } else {
                vfloat4 z = {0.f, 0.f, 0.f, 0.f};
                v[j] = z;
            }
        }
#pragma unroll
        for (int j = 0; j < 4; ++j) {
            int base = (256 + lane + 64 * j) * 4;
            if (v[j][0] > 0.5f) pos = base;
            if (v[j][1] > 0.5f) pos = base + 1;
            if (v[j][2] > 0.5f) pos = base + 2;
            if (v[j][3] > 0.5f) pos = base + 3;
        }
    }
    // exactly one lane found the 1.0; max-reduce the position across the wave
#pragma unroll
    for (int o = 32; o > 0; o >>= 1) pos = max(pos, __shfl_xor(pos, o, 64));
    if (lane == 0) idx[wave] = pos;
}

// ---------------- g kernel: g[row,0:160] = logmap0(hnn1(proj(expmap0(logmap0(x))))) ----
// Analytic-norm chain: |expmap0(u)| = tanh(|u|), |logmap0(p)| = artanh(|p|),
// |proj(x)| = min(|x|, MAXNORM), |s*x| = s*|x|. Only 6 reductions are genuine.
__global__ __launch_bounds__(256, 4) void g_kernel(const float* __restrict__ xin,
                                                   const float* __restrict__ W1,
                                                   const float* __restrict__ b1,
                                                   float* __restrict__ g) {
    int lane = threadIdx.x & 63;
    int wave = (int)blockIdx.x * 4 + (int)(threadIdx.x >> 6);  // 0..7999
    bool j2ok = lane < (H1 - 128);  // lane < 32 handles third chunk

    // --- load agent row (lanes 0..31 hold components) ---
    float x = (lane < DD) ? xin[wave * DD + lane] : 0.f;

    // feats = logmap0(x)
    float n = fmaxf(sqrtf(wave_sum(x * x)), MINN);          // reduce #1
    float fa = artanh_f(n);
    float f = (fa / n) * x;
    // p = proj(expmap0(feats));  |f| = artanh(n), |p| = tanh(|f|)
    float fn = fmaxf(fa, MINN);
    float tp = tanhf(fn);
    float p = (tp / fn) * f;
    float pn = tp;
    if (pn > MAXNORM) p *= MAXNORM / pn;
    float xn = fmaxf(fminf(pn, MAXNORM), MINN);             // |p| after proj

    // mx = W1 @ p  (each lane: rows lane, lane+64, lane+128)
    float mx0 = 0.f, mx1 = 0.f, mx2 = 0.f;
#pragma unroll
    for (int d = 0; d < DD; ++d) {
        float pd = __shfl(p, d, 64);
        mx0 += W1[lane * DD + d] * pd;
        mx1 += W1[(lane + 64) * DD + d] * pd;
        if (j2ok) mx2 += W1[(lane + 128) * DD + d] * pd;
    }
    float m2 = mx0 * mx0 + mx1 * mx1 + (j2ok ? mx2 * mx2 : 0.f);
    float mxn = fmaxf(sqrtf(wave_sum(m2)), MINN);           // reduce #2
    float tr = tanhf(mxn / xn * artanh_f(xn));
    float sc = tr / mxn;
    float r0 = sc * mx0, r1 = sc * mx1, r2 = sc * mx2;
    // proj: |r| = tr (tanh arg positive)
    float rn = tr;
    if (rn > MAXNORM) { float s = MAXNORM / rn; r0 *= s; r1 *= s; r2 *= s; }
    rn = fminf(rn, MAXNORM);

    // hb = proj(expmap0(b1))  (b1 == 0 in practice; general path kept)
    float bb0 = b1[lane], bb1 = b1[lane + 64], bb2 = j2ok ? b1[lane + 128] : 0.f;
    float bn = fmaxf(sqrtf(wave_sum(bb0 * bb0 + bb1 * bb1 + bb2 * bb2)), MINN);  // reduce #3
    float tb = tanhf(bn);
    float bs = tb / bn;
    float h0 = bs * bb0, h1 = bs * bb1, h2 = bs * bb2;
    float hn = tb;
    if (hn > MAXNORM) { float s = MAXNORM / hn; h0 *= s; h1 *= s; h2 *= s; }
    hn = fminf(hn, MAXNORM);

    // mobius_add(r, h): x2s = rn^2, y2s = hn^2 analytic; only cross term reduced
    float x2s = rn * rn;
    float y2s = hn * hn;
    float xys = wave_sum(r0 * h0 + r1 * h1 + (j2ok ? r2 * h2 : 0.f));  // reduce #4
    float ca = 1.f + 2.f * xys + y2s;
    float cb = 1.f - x2s;
    float den = fmaxf(1.f + 2.f * xys + x2s * y2s, MINN);
    float a0 = (ca * r0 + cb * h0) / den;
    float a1 = (ca * r1 + cb * h1) / den;
    float a2 = (ca * r2 + cb * h2) / den;
    // proj
    float an = fmaxf(sqrtf(wave_sum(a0 * a0 + a1 * a1 + (j2ok ? a2 * a2 : 0.f))), MINN);  // reduce #5
    if (an > MAXNORM) { float s = MAXNORM / an; a0 *= s; a1 *= s; a2 *= s; }
    float an2 = fmaxf(fminf(an, MAXNORM), MINN);

    // xt = relu(logmap0(a)) — relu changes the norm, so reduce again
    float ls = artanh_f(an2) / an2;
    float t0 = fmaxf(ls * a0, 0.f), t1 = fmaxf(ls * a1, 0.f), t2 = fmaxf(ls * a2, 0.f);
    float tn = fmaxf(sqrtf(wave_sum(t0 * t0 + t1 * t1 + (j2ok ? t2 * t2 : 0.f))), MINN);  // reduce #6
    // y = proj(expmap0(xt)); |y| = tanh(tn); g = logmap0(y)
    float te = tanhf(tn);
    float es = te / tn;
    float y0 = es * t0, y1 = es * t1, y2 = es * t2;
    float yn = te;
    float s2 = (yn > MAXNORM) ? (MAXNORM / yn) : 1.f;
    y0 *= s2; y1 *= s2; y2 *= s2;
    float yn2 = fmaxf(fminf(yn, MAXNORM), MINN);
    float gs = artanh_f(yn2) / yn2;

    float* go = g + (size_t)wave * H1;
    go[lane] = gs * y0;
    go[lane + 64] = gs * y1;
    if (j2ok) go[lane + 128] = gs * y2;
}

// ---------------- Kernel 3: fused attention + output layer, wave per (b,n) --
__global__ __launch_bounds__(256, 4) void fused_att_out_kernel(const float* __restrict__ g,
                                                               const int* __restrict__ idx,
                                                               const float* __restrict__ W2,
                                                               const float* __restrict__ b2,
                                                               float* __restrict__ out,
                                                               float* __restrict__ att_out) {
    int wave = (blockIdx.x * blockDim.x + threadIdx.x) >> 6;
    int lane = threadIdx.x & 63;
    if (wave >= BB * NN) return;
    int r = wave;
    int b = r / NN;
    int d = lane & 31;  // both 32-halves do identical work

    // q[d][h]
    const float* gq = g + (size_t)r * H1;
    float q[HEAD];
#pragma unroll
    for (int h = 0; h < HEAD; ++h) q[h] = gq[d * HEAD + h];

    // load all 5 neighbor indices, then all 5 kv rows (max memory parallelism),
    // then reduce the 25 dot products
    int nb[KK];
#pragma unroll
    for (int k = 0; k < KK; ++k) nb[k] = idx[r * KK + k];
    float kv[KK][HEAD];
#pragma unroll
    for (int k = 0; k < KK; ++k) {
        const float* gk = g + (size_t)(b * NN + nb[k]) * H1 + d * HEAD;
#pragma unroll
        for (int h = 0; h < HEAD; ++h) kv[k][h] = gk[h];
    }
    float s[KK][HEAD];
#pragma unroll
    for (int k = 0; k < KK; ++k)
#pragma unroll
        for (int h = 0; h < HEAD; ++h) s[k][h] = wave_sum32(q[h] * kv[k][h]);

    // softmax over k per head (redundant per lane; all lanes hold s)
    float att[HEAD][KK];
#pragma unroll
    for (int h = 0; h < HEAD; ++h) {
        float mxv = s[0][h];
#pragma unroll
        for (int k = 1; k < KK; ++k) mxv = fmaxf(mxv, s[k][h]);
        float sum = 0.f;
#pragma unroll
        for (int k = 0; k < KK; ++k) { att[h][k] = expf(s[k][h] - mxv); sum += att[h][k]; }
        float inv = 1.f / sum;
#pragma unroll
        for (int k = 0; k < KK; ++k) att[h][k] *= inv;
    }
    // att_record: [r][h][k], lanes 0..24 write
    if (lane < HEAD * KK) {
        int h = lane / KK, k = lane % KK;
        att_out[(size_t)r * HEAD * KK + lane] = att[h][k];
    }

    // o[d] = mean over heads of sum_k att*kv
    float o = 0.f;
#pragma unroll
    for (int h = 0; h < HEAD; ++h)
#pragma unroll
        for (int k = 0; k < KK; ++k) o += att[h][k] * kv[k][h];
    o *= (1.f / HEAD);

    // ---- proj(expmap0(o)); |expmap0(o)| = tanh(|o|) ----
    float n = fmaxf(sqrtf(wave_sum32(o * o)), MINN);        // reduce #1
    float to = tanhf(n);
    o *= to / n;
    float on = to;
    if (on > MAXNORM) o *= MAXNORM / on;
    float xn = fmaxf(fminf(on, MAXNORM), MINN);

    // ---- hnn_layer(o, W2, b2) ----
    // mx[j] = W2[j,:] @ o  (j = lane&31)
    float mx = 0.f;
#pragma unroll
    for (int dd = 0; dd < HDIM; ++dd) {
        float od = __shfl(o, dd, 64);
        mx += W2[d * HDIM + dd] * od;
    }
    float mxn = fmaxf(sqrtf(wave_sum32(mx * mx)), MINN);    // reduce #2
    float tr = tanhf(mxn / xn * artanh_f(xn));
    mx *= tr / mxn;
    float rn = tr;
    if (rn > MAXNORM) mx *= MAXNORM / rn;
    rn = fminf(rn, MAXNORM);

    // hb = proj(expmap0(b2))
    float hb = b2[d];
    float bn = fmaxf(sqrtf(wave_sum32(hb * hb)), MINN);     // reduce #3
    float tb = tanhf(bn);
    hb *= tb / bn;
    float hn = tb;
    if (hn > MAXNORM) hb *= MAXNORM / hn;
    hn = fminf(hn, MAXNORM);

    // mobius_add(mx, hb): x2s/y2s analytic, cross term reduced
    float x2s = rn * rn;
    float y2s = hn * hn;
    float xys = wave_sum32(mx * hb);                        // reduce #4
    float ca = 1.f + 2.f * xys + y2s;
    float cb = 1.f - x2s;
    float den = fmaxf(1.f + 2.f * xys + x2s * y2s, MINN);
    float a = (ca * mx + cb * hb) / den;
    // proj
    float an = fmaxf(sqrtf(wave_sum32(a * a)), MINN);       // reduce #5
    if (an > MAXNORM) a *= MAXNORM / an;
    float an2 = fmaxf(fminf(an, MAXNORM), MINN);

    // xt = relu(logmap0(a))
    a = fmaxf((artanh_f(an2) / an2) * a, 0.f);
    // proj(expmap0(xt)); |expmap0(xt)| = tanh(|xt|)
    float tn = fmaxf(sqrtf(wave_sum32(a * a)), MINN);       // reduce #6
    float te = tanhf(tn);
    a *= te / tn;
    float yn = te;
    if (yn > MAXNORM) a *= MAXNORM / yn;

    if (lane < HDIM) out[(size_t)r * HDIM + lane] = a;
}

extern "C" void kernel_launch(void* const* d_in, const int* in_sizes, int n_in,
                              void* d_out, int out_size, void* d_ws, size_t ws_size,
                              hipStream_t stream) {
    const float* in_feats = (const float*)d_in[0];
    const float* in_nei = (const float*)d_in[1];
    const float* W1 = (const float*)d_in[2];
    const float* b1 = (const float*)d_in[3];
    const float* W2 = (const float*)d_in[4];
    const float* b2 = (const float*)d_in[5];

    // workspace layout: idx[40000] ints, then g[8000*160] floats
    int* idx = (int*)d_ws;
    size_t idx_bytes = ((size_t)BB * NN * KK * sizeof(int) + 255) & ~(size_t)255;
    float* g = (float*)((char*)d_ws + idx_bytes);

    float* out = (float*)d_out;                      // [B,N,32] = 256000 floats
    float* att = out + (size_t)BB * NN * HDIM;       // [B,N,head,K] = 200000 floats

    // Three kernels:
    // 1) g table (short, VALU-bound), 2) two-batch NT scan (~240 MB expected,
    //    fits inside the concurrent harness-fill's bandwidth shadow),
    // 3) fused attention + output layer.
    hipLaunchKernelGGL(g_kernel, dim3(G_BLOCKS), dim3(256), 0, stream,
                       in_feats, W1, b1, g);
    hipLaunchKernelGGL(scan_kernel, dim3(SCAN_BLOCKS), dim3(256), 0, stream,
                       in_nei, idx);
    hipLaunchKernelGGL(fused_att_out_kernel, dim3((BB * NN * 64 + 255) / 256), dim3(256), 0, stream,
                       g, idx, W2, b2, out, att);
}

// Round 7
// 503.730 us; speedup vs baseline: 1.0817x; 1.0022x over previous
//
#include <hip/hip_runtime.h>
#include <math.h>

#define BB 4
#define NN 2000
#define KK 5
#define DD 32
#define H1 160
#define HEAD 5
#define HDIM 32
#define MAXNORM 0.996f
#define MINN 1e-15f

#define NROWS (BB * NN * KK)        // 40000 one-hot rows
#define F4_PER_ROW (NN / 4)         // 500 float4 per row
#define G_BLOCKS 2000               // 8000 g-rows, 4 waves/block
#define MEGA_BLOCKS 2000            // 8000 (b,n) waves, 4 waves/block

typedef float vfloat4 __attribute__((ext_vector_type(4)));

__device__ __forceinline__ float artanh_f(float x) {
    x = fminf(fmaxf(x, -1.0f + 1e-7f), 1.0f - 1e-7f);
    return 0.5f * (log1pf(x) - log1pf(-x));
}

// sum over a full 64-lane wave
__device__ __forceinline__ float wave_sum(float v) {
#pragma unroll
    for (int o = 32; o > 0; o >>= 1) v += __shfl_xor(v, o, 64);
    return v;
}

// sum within each 32-lane half (both halves hold identical data in our usage)
__device__ __forceinline__ float wave_sum32(float v) {
#pragma unroll
    for (int o = 16; o > 0; o >>= 1) v += __shfl_xor(v, o, 64);
    return v;
}

// ---------------- g kernel: g[row,0:160] = logmap0(hnn1(proj(expmap0(logmap0(x))))) ----
// Analytic-norm chain: |expmap0(u)| = tanh(|u|), |logmap0(p)| = artanh(|p|),
// |proj(x)| = min(|x|, MAXNORM), |s*x| = s*|x|. Only 6 reductions are genuine.
__global__ __launch_bounds__(256, 4) void g_kernel(const float* __restrict__ xin,
                                                   const float* __restrict__ W1,
                                                   const float* __restrict__ b1,
                                                   float* __restrict__ g) {
    int lane = threadIdx.x & 63;
    int wave = (int)blockIdx.x * 4 + (int)(threadIdx.x >> 6);  // 0..7999
    bool j2ok = lane < (H1 - 128);  // lane < 32 handles third chunk

    // --- load agent row (lanes 0..31 hold components) ---
    float x = (lane < DD) ? xin[wave * DD + lane] : 0.f;

    // feats = logmap0(x)
    float n = fmaxf(sqrtf(wave_sum(x * x)), MINN);          // reduce #1
    float fa = artanh_f(n);
    float f = (fa / n) * x;
    // p = proj(expmap0(feats));  |f| = artanh(n), |p| = tanh(|f|)
    float fn = fmaxf(fa, MINN);
    float tp = tanhf(fn);
    float p = (tp / fn) * f;
    float pn = tp;
    if (pn > MAXNORM) p *= MAXNORM / pn;
    float xn = fmaxf(fminf(pn, MAXNORM), MINN);             // |p| after proj

    // mx = W1 @ p  (each lane: rows lane, lane+64, lane+128)
    float mx0 = 0.f, mx1 = 0.f, mx2 = 0.f;
#pragma unroll
    for (int d = 0; d < DD; ++d) {
        float pd = __shfl(p, d, 64);
        mx0 += W1[lane * DD + d] * pd;
        mx1 += W1[(lane + 64) * DD + d] * pd;
        if (j2ok) mx2 += W1[(lane + 128) * DD + d] * pd;
    }
    float m2 = mx0 * mx0 + mx1 * mx1 + (j2ok ? mx2 * mx2 : 0.f);
    float mxn = fmaxf(sqrtf(wave_sum(m2)), MINN);           // reduce #2
    float tr = tanhf(mxn / xn * artanh_f(xn));
    float sc = tr / mxn;
    float r0 = sc * mx0, r1 = sc * mx1, r2 = sc * mx2;
    // proj: |r| = tr (tanh arg positive)
    float rn = tr;
    if (rn > MAXNORM) { float s = MAXNORM / rn; r0 *= s; r1 *= s; r2 *= s; }
    rn = fminf(rn, MAXNORM);

    // hb = proj(expmap0(b1))  (b1 == 0 in practice; general path kept)
    float bb0 = b1[lane], bb1 = b1[lane + 64], bb2 = j2ok ? b1[lane + 128] : 0.f;
    float bn = fmaxf(sqrtf(wave_sum(bb0 * bb0 + bb1 * bb1 + bb2 * bb2)), MINN);  // reduce #3
    float tb = tanhf(bn);
    float bs = tb / bn;
    float h0 = bs * bb0, h1 = bs * bb1, h2 = bs * bb2;
    float hn = tb;
    if (hn > MAXNORM) { float s = MAXNORM / hn; h0 *= s; h1 *= s; h2 *= s; }
    hn = fminf(hn, MAXNORM);

    // mobius_add(r, h): x2s = rn^2, y2s = hn^2 analytic; only cross term reduced
    float x2s = rn * rn;
    float y2s = hn * hn;
    float xys = wave_sum(r0 * h0 + r1 * h1 + (j2ok ? r2 * h2 : 0.f));  // reduce #4
    float ca = 1.f + 2.f * xys + y2s;
    float cb = 1.f - x2s;
    float den = fmaxf(1.f + 2.f * xys + x2s * y2s, MINN);
    float a0 = (ca * r0 + cb * h0) / den;
    float a1 = (ca * r1 + cb * h1) / den;
    float a2 = (ca * r2 + cb * h2) / den;
    // proj
    float an = fmaxf(sqrtf(wave_sum(a0 * a0 + a1 * a1 + (j2ok ? a2 * a2 : 0.f))), MINN);  // reduce #5
    if (an > MAXNORM) { float s = MAXNORM / an; a0 *= s; a1 *= s; a2 *= s; }
    float an2 = fmaxf(fminf(an, MAXNORM), MINN);

    // xt = relu(logmap0(a)) — relu changes the norm, so reduce again
    float ls = artanh_f(an2) / an2;
    float t0 = fmaxf(ls * a0, 0.f), t1 = fmaxf(ls * a1, 0.f), t2 = fmaxf(ls * a2, 0.f);
    float tn = fmaxf(sqrtf(wave_sum(t0 * t0 + t1 * t1 + (j2ok ? t2 * t2 : 0.f))), MINN);  // reduce #6
    // y = proj(expmap0(xt)); |y| = tanh(tn); g = logmap0(y)
    float te = tanhf(tn);
    float es = te / tn;
    float y0 = es * t0, y1 = es * t1, y2 = es * t2;
    float yn = te;
    float s2 = (yn > MAXNORM) ? (MAXNORM / yn) : 1.f;
    y0 *= s2; y1 *= s2; y2 *= s2;
    float yn2 = fmaxf(fminf(yn, MAXNORM), MINN);
    float gs = artanh_f(yn2) / yn2;

    float* go = g + (size_t)wave * H1;
    go[lane] = gs * y0;
    go[lane + 64] = gs * y1;
    if (j2ok) go[lane + 128] = gs * y2;
}

// ---------------- mega kernel: scan own 5 one-hot rows + attention + output ----
// Wave per (b,n). Dependency insight: attention row r needs ONLY its own 5
// one-hot rows' indices (rows r*5..r*5+4 of in_nei) plus arbitrary g rows
// (g_kernel already done). So the scan fuses here: phase 1 issues 20
// independent NT float4 loads (5 rows x cols 0..1023, 20 KB/wave in flight),
// phase 2 covers cols 1024..1999 for the ~49% unresolved rows. Indices are
// wave-reduced in-register (packed 64-bit OR, one 6-round shuffle) - no idx
// array, no third kernel, no serial tail after the scan.
__global__ __launch_bounds__(256) void scan_att_out_kernel(const float* __restrict__ nei,
                                                           const float* __restrict__ g,
                                                           const float* __restrict__ W2,
                                                           const float* __restrict__ b2,
                                                           float* __restrict__ out,
                                                           float* __restrict__ att_out) {
    int lane = threadIdx.x & 63;
    int r = (int)((blockIdx.x * 256u + threadIdx.x) >> 6);   // 0..7999 exact
    int b = r / NN;

    // ---- scan: 2-phase, 5 rows per wave ----
    int pos[KK];
    {
        const float* rows[KK];
#pragma unroll
        for (int k = 0; k < KK; ++k)
            rows[k] = nei + (size_t)(r * KK + k) * NN;

        vfloat4 v[KK][4];
#pragma unroll
        for (int k = 0; k < KK; ++k)
#pragma unroll
            for (int j = 0; j < 4; ++j)
                v[k][j] = __builtin_nontemporal_load((const vfloat4*)rows[k] + (lane + 64 * j));
#pragma unroll
        for (int k = 0; k < KK; ++k) {
            pos[k] = -1;
#pragma unroll
            for (int j = 0; j < 4; ++j) {
                int base = (lane + 64 * j) * 4;
                if (v[k][j][0] > 0.5f) pos[k] = base;
                if (v[k][j][1] > 0.5f) pos[k] = base + 1;
                if (v[k][j][2] > 0.5f) pos[k] = base + 2;
                if (v[k][j][3] > 0.5f) pos[k] = base + 3;
            }
        }
        // phase 2 for unresolved rows (wave-uniform branch per row)
#pragma unroll
        for (int k = 0; k < KK; ++k) {
            if (__ballot(pos[k] >= 0) == 0ull) {
                vfloat4 w[4];
#pragma unroll
                for (int j = 0; j < 4; ++j) {
                    int e = 256 + lane + 64 * j;
                    if (e < F4_PER_ROW) {
                        w[j] = __builtin_nontemporal_load((const vfloat4*)rows[k] + e);
                    } else {
                        vfloat4 z = {0.f, 0.f, 0.f, 0.f};
                        w[j] = z;
                    }
                }
#pragma unroll
                for (int j = 0; j < 4; ++j) {
                    int base = (256 + lane + 64 * j) * 4;
                    if (w[j][0] > 0.5f) pos[k] = base;
                    if (w[j][1] > 0.5f) pos[k] = base + 1;
                    if (w[j][2] > 0.5f) pos[k] = base + 2;
                    if (w[j][3] > 0.5f) pos[k] = base + 3;
                }
            }
        }
    }
    // pack the 5 positions (11 bits each, +1 bias so "found 0" != "not found")
    // into one 64-bit word; exactly one lane holds each row's value -> OR-reduce.
    unsigned long long packed = 0ull;
#pragma unroll
    for (int k = 0; k < KK; ++k)
        if (pos[k] >= 0)
            packed |= (unsigned long long)(pos[k] + 1) << (12 * k);
#pragma unroll
    for (int o = 32; o > 0; o >>= 1) packed |= __shfl_xor(packed, o, 64);

    int nb[KK];
#pragma unroll
    for (int k = 0; k < KK; ++k)
        nb[k] = (int)((packed >> (12 * k)) & 0xFFFull) - 1;

    // ---- attention ----
    int d = lane & 31;  // both 32-halves do identical work
    const float* gq = g + (size_t)r * H1;
    float q[HEAD];
#pragma unroll
    for (int h = 0; h < HEAD; ++h) q[h] = gq[d * HEAD + h];

    float kv[KK][HEAD];
#pragma unroll
    for (int k = 0; k < KK; ++k) {
        const float* gk = g + (size_t)(b * NN + nb[k]) * H1 + d * HEAD;
#pragma unroll
        for (int h = 0; h < HEAD; ++h) kv[k][h] = gk[h];
    }
    float s[KK][HEAD];
#pragma unroll
    for (int k = 0; k < KK; ++k)
#pragma unroll
        for (int h = 0; h < HEAD; ++h) s[k][h] = wave_sum32(q[h] * kv[k][h]);

    // softmax over k per head (redundant per lane; all lanes hold s)
    float att[HEAD][KK];
#pragma unroll
    for (int h = 0; h < HEAD; ++h) {
        float mxv = s[0][h];
#pragma unroll
        for (int k = 1; k < KK; ++k) mxv = fmaxf(mxv, s[k][h]);
        float sum = 0.f;
#pragma unroll
        for (int k = 0; k < KK; ++k) { att[h][k] = expf(s[k][h] - mxv); sum += att[h][k]; }
        float inv = 1.f / sum;
#pragma unroll
        for (int k = 0; k < KK; ++k) att[h][k] *= inv;
    }
    // att_record: [r][h][k], lanes 0..24 write
    if (lane < HEAD * KK) {
        int h = lane / KK, k = lane % KK;
        att_out[(size_t)r * HEAD * KK + lane] = att[h][k];
    }

    // o[d] = mean over heads of sum_k att*kv
    float o = 0.f;
#pragma unroll
    for (int h = 0; h < HEAD; ++h)
#pragma unroll
        for (int k = 0; k < KK; ++k) o += att[h][k] * kv[k][h];
    o *= (1.f / HEAD);

    // ---- proj(expmap0(o)); |expmap0(o)| = tanh(|o|) ----
    float n = fmaxf(sqrtf(wave_sum32(o * o)), MINN);        // reduce #1
    float to = tanhf(n);
    o *= to / n;
    float on = to;
    if (on > MAXNORM) o *= MAXNORM / on;
    float xn = fmaxf(fminf(on, MAXNORM), MINN);

    // ---- hnn_layer(o, W2, b2) ----
    float mx = 0.f;
#pragma unroll
    for (int dd = 0; dd < HDIM; ++dd) {
        float od = __shfl(o, dd, 64);
        mx += W2[d * HDIM + dd] * od;
    }
    float mxn = fmaxf(sqrtf(wave_sum32(mx * mx)), MINN);    // reduce #2
    float tr = tanhf(mxn / xn * artanh_f(xn));
    mx *= tr / mxn;
    float rn = tr;
    if (rn > MAXNORM) mx *= MAXNORM / rn;
    rn = fminf(rn, MAXNORM);

    // hb = proj(expmap0(b2))
    float hb = b2[d];
    float bn = fmaxf(sqrtf(wave_sum32(hb * hb)), MINN);     // reduce #3
    float tb = tanhf(bn);
    hb *= tb / bn;
    float hn = tb;
    if (hn > MAXNORM) hb *= MAXNORM / hn;
    hn = fminf(hn, MAXNORM);

    // mobius_add(mx, hb): x2s/y2s analytic, cross term reduced
    float x2s = rn * rn;
    float y2s = hn * hn;
    float xys = wave_sum32(mx * hb);                        // reduce #4
    float ca = 1.f + 2.f * xys + y2s;
    float cb = 1.f - x2s;
    float den = fmaxf(1.f + 2.f * xys + x2s * y2s, MINN);
    float a = (ca * mx + cb * hb) / den;
    // proj
    float an = fmaxf(sqrtf(wave_sum32(a * a)), MINN);       // reduce #5
    if (an > MAXNORM) a *= MAXNORM / an;
    float an2 = fmaxf(fminf(an, MAXNORM), MINN);

    // xt = relu(logmap0(a))
    a = fmaxf((artanh_f(an2) / an2) * a, 0.f);
    // proj(expmap0(xt)); |expmap0(xt)| = tanh(|xt|)
    float tn = fmaxf(sqrtf(wave_sum32(a * a)), MINN);       // reduce #6
    float te = tanhf(tn);
    a *= te / tn;
    float yn = te;
    if (yn > MAXNORM) a *= MAXNORM / yn;

    if (lane < HDIM) out[(size_t)r * HDIM + lane] = a;
}

extern "C" void kernel_launch(void* const* d_in, const int* in_sizes, int n_in,
                              void* d_out, int out_size, void* d_ws, size_t ws_size,
                              hipStream_t stream) {
    const float* in_feats = (const float*)d_in[0];
    const float* in_nei = (const float*)d_in[1];
    const float* W1 = (const float*)d_in[2];
    const float* b1 = (const float*)d_in[3];
    const float* W2 = (const float*)d_in[4];
    const float* b2 = (const float*)d_in[5];

    // workspace: g[8000*160] floats only (indices now live in registers)
    float* g = (float*)d_ws;

    float* out = (float*)d_out;                      // [B,N,32] = 256000 floats
    float* att = out + (size_t)BB * NN * HDIM;       // [B,N,head,K] = 200000 floats

    // Two kernels:
    // 1) g table (short, VALU-bound);
    // 2) fused scan + attention + output layer: wave per (b,n) scans its own
    //    5 one-hot rows (2-phase NT, ~30 KB/wave expected) and consumes the
    //    indices in-register. No idx round-trip, no third serial kernel.
    hipLaunchKernelGGL(g_kernel, dim3(G_BLOCKS), dim3(256), 0, stream,
                       in_feats, W1, b1, g);
    hipLaunchKernelGGL(scan_att_out_kernel, dim3(MEGA_BLOCKS), dim3(256), 0, stream,
                       in_nei, g, W2, b2, out, att);
}